// Round 7
// baseline (144.660 us; speedup 1.0000x reference)
//
#include <hip/hip_runtime.h>
#include <hip/hip_bf16.h>

// CondLaneHead via bf16 MFMA 16x16x32, 3 layers fused. Round 7.
// 32 instances (4 img x 8), C=64, H=160, W=256, L=40960 px.
//
// r4/r5/r6 all pinned at ~62us with different single-pipe fixes -> this round
// cuts LDS-pipe, VALU, and VMEM together:
//  - 256 px/block (one image row), nt=4 per wave: weight reads amortize 2x.
//  - layer1 K=96: b0/wx/wy folded into MFMA as hi/lo bf16 aug rows (fx,fy
//    integers <=255 are EXACT in bf16); no C-init vec reads, C starts at 0.
//  - h C->B transform via swizzled LDS round-trip (r5-verified pattern),
//    split into two nt-halves reusing one 4KB/wave buffer (in-order DS).
//  - LDS overlay: xs(32KB) dead after B-frags cached in regs -> weights
//    (21KB, single buffer + reg-prefetch) + h(16KB) overlay it. 37.9KB,
//    launch_bounds(256,3) -> 3 blocks/CU.
//
// Frag layouts (m89/m120-verified): A[m=lane&15][k=(lane>>4)*8+j],
// B[k=(lane>>4)*8+j][n=lane&15], D[row=(lane>>4)*4+r][col=lane&15].
//
// ws per instance (ISTRIDE=21504B):
//   [0,12288)     w0 A-frags K=96, frag(mt,kst)=mt*3+kst, 1KB each;
//                 kst=2 is aug: k64=b0_hi k65=wx_hi k66=wx_lo k67=wy_hi
//                 k68=wy_lo k69=b0_lo k70..95=0
//   [12288,20480) w1 A-frags, frag(mt,kst)=mt*2+kst
//   [20480,21504) vec: b1[64] w2[64] b2 (floats)

#define NP 8513
#define HW 40960
#define ISTRIDE 21504
#define OFF_W1 12288
#define OFF_VEC 20480

typedef __attribute__((ext_vector_type(8))) short bf16x8;
typedef __attribute__((ext_vector_type(4))) float f32x4;

__device__ inline unsigned short f2bf(float f) {
  union { float f; unsigned u; } v; v.f = f;
  unsigned r = v.u + 0x7fffu + ((v.u >> 16) & 1u);   // RNE
  return (unsigned short)(r >> 16);
}
__device__ inline float bf2f(unsigned short b) {
  union { unsigned u; float f; } v; v.u = ((unsigned)b) << 16;
  return v.f;
}
__device__ inline unsigned pk2(float a, float b) {   // [lo=a, hi=b] bf16x2
  __hip_bfloat162 h = __float22bfloat162_rn(float2{a, b});
  union { __hip_bfloat162 h; unsigned u; } v; v.h = h;
  return v.u;
}

__global__ void condlane_prep(const float* __restrict__ params,
                              char* __restrict__ ws) {
  const int inst = blockIdx.x >> 1, part = blockIdx.x & 1;
  const float* __restrict__ p = params + inst * NP;
  char* base = ws + inst * ISTRIDE;
  if (part == 0) {           // w0 A-frags incl. aug kstep
    unsigned short* dst = (unsigned short*)base;
#pragma unroll
    for (int it = 0; it < 24; it++) {
      const int e = it * 256 + threadIdx.x;          // 0..6143
      const int frag = e >> 9, lane = (e >> 3) & 63, j = e & 7;
      const int mt = frag / 3, kst = frag % 3;
      const int m = mt * 16 + (lane & 15);
      const int kl = ((lane >> 4) << 3) + j;
      unsigned short bv;
      if (kst < 2) bv = f2bf(p[m * 66 + 2 + kst * 32 + kl]);
      else if (kl == 0) bv = f2bf(p[8384 + m]);                  // b0_hi
      else if (kl == 1) bv = f2bf(p[m * 66]);                    // wx_hi
      else if (kl == 2) { float w = p[m * 66];     bv = f2bf(w - bf2f(f2bf(w))); }
      else if (kl == 3) bv = f2bf(p[m * 66 + 1]);                // wy_hi
      else if (kl == 4) { float w = p[m * 66 + 1]; bv = f2bf(w - bf2f(f2bf(w))); }
      else if (kl == 5) { float w = p[8384 + m];   bv = f2bf(w - bf2f(f2bf(w))); }
      else bv = 0;
      dst[e] = bv;
    }
  } else {                   // w1 A-frags + vec
    unsigned short* dst = (unsigned short*)(base + OFF_W1);
#pragma unroll
    for (int it = 0; it < 16; it++) {
      const int e = it * 256 + threadIdx.x;
      const int frag = e >> 9, lane = (e >> 3) & 63, j = e & 7;
      const int m = (frag >> 1) * 16 + (lane & 15);
      const int k = (frag & 1) * 32 + ((lane >> 4) << 3) + j;
      dst[e] = f2bf(p[4224 + m * 64 + k]);
    }
    float* vec = (float*)(base + OFF_VEC);
    const int t = threadIdx.x;
    if (t < 64) { vec[t] = p[8448 + t]; vec[64 + t] = p[8320 + t]; }
    else if (t == 64) vec[128] = p[8512] - 2.19f;
  }
}

__global__ __launch_bounds__(256, 3) void condlane_main(
    const float* __restrict__ x, const char* __restrict__ ws,
    float* __restrict__ out) {
  // overlay: [0,32768) xs (stage-x, dies after bfr) ; then
  //          [0,21504) weights + [21504,37888) h (4KB per wave)
  __shared__ __align__(16) char smem[37888];
  unsigned short* const xs = (unsigned short*)smem;
  char* const wl = smem;
  const int img = blockIdx.y, bx = blockIdx.x;     // bx = image row
  const int tid = threadIdx.x, lane = tid & 63, wave = tid >> 6;
  const int col = lane & 15, q = lane >> 4, sw = lane & 7;
  const char* const wsb = ws + img * 8 * ISTRIDE;

  // issue inst-0 weight loads early (L2) -- consumed after x-stage
  uint4 st[6];
#pragma unroll
  for (int j = 0; j < 6; j++)
    if (j < 5 || tid < 64) st[j] = *(const uint4*)(wsb + j * 4096 + tid * 16);

  // ---- stage x row (256 px): thread = one pixel, 64 ch, swizzled ----
  {
    const float* gx = x + img * 64 * HW + bx * 256 + tid;
    unsigned short* row = xs + tid * 64;
    const int psw = tid & 7;
#pragma unroll
    for (int cb = 0; cb < 8; cb++) {
      union { bf16x8 v; unsigned short s[8]; } u;
#pragma unroll
      for (int j = 0; j < 8; j++) u.s[j] = f2bf(gx[(cb * 8 + j) * HW]);
      *(bf16x8*)(row + ((cb ^ psw) << 3)) = u.v;
    }
  }
  __syncthreads();

  // ---- x B-frags to regs once; reused across all 8 instances ----
  bf16x8 bfr[4][2];
#pragma unroll
  for (int nt = 0; nt < 4; nt++)
#pragma unroll
    for (int ks = 0; ks < 2; ks++) {
      const int row = wave * 64 + nt * 16 + col;
      bfr[nt][ks] = *(const bf16x8*)(xs + row * 64 +
                                     (((ks * 4 + q) ^ (row & 7)) << 3));
    }
  // aug B-frags (k=64..95): q=0 lanes hold [1, fx, fx, fy, fy, 1, 0, 0]
  bf16x8 baug[4];
  {
    const unsigned short fyb = f2bf((float)bx);
#pragma unroll
    for (int nt = 0; nt < 4; nt++) {
      const unsigned short fxb = f2bf((float)(wave * 64 + nt * 16 + col));
      union { bf16x8 v; unsigned short s[8]; } u;
      u.s[0] = (q == 0) ? (unsigned short)0x3F80 : (unsigned short)0;
      u.s[1] = (q == 0) ? fxb : (unsigned short)0;
      u.s[2] = u.s[1];
      u.s[3] = (q == 0) ? fyb : (unsigned short)0;
      u.s[4] = u.s[3];
      u.s[5] = u.s[0];
      u.s[6] = 0; u.s[7] = 0;
      baug[nt] = u.v;
    }
  }
  __syncthreads();   // all bfr reads done before weights overwrite xs

  // write inst-0 weights into LDS
#pragma unroll
  for (int j = 0; j < 6; j++)
    if (j < 5 || tid < 64) *(uint4*)(wl + j * 4096 + tid * 16) = st[j];
  __syncthreads();

  unsigned short* const hw = (unsigned short*)(smem + 21504) + wave * 2048;
  const f32x4 z4 = {0.f, 0.f, 0.f, 0.f};
  float* const outb = out + img * 8 * HW + bx * 256 + wave * 64 + lane;

  for (int i = 0; i < 8; i++) {
    // prefetch next instance's weights to regs (overlaps compute)
    if (i < 7) {
      const char* src = wsb + (i + 1) * ISTRIDE;
#pragma unroll
      for (int j = 0; j < 6; j++)
        if (j < 5 || tid < 64) st[j] = *(const uint4*)(src + j * 4096 + tid * 16);
    }
    // ---- layer 1: K=96 (2 x-ksteps + aug kstep), C starts at 0 ----
    f32x4 acc[4][4];
#pragma unroll
    for (int mt = 0; mt < 4; mt++) {
      const bf16x8 a0 = *(const bf16x8*)(wl + (mt * 3 + 0) * 1024 + lane * 16);
      const bf16x8 a1 = *(const bf16x8*)(wl + (mt * 3 + 1) * 1024 + lane * 16);
      const bf16x8 a2 = *(const bf16x8*)(wl + (mt * 3 + 2) * 1024 + lane * 16);
#pragma unroll
      for (int nt = 0; nt < 4; nt++) {
        f32x4 c = __builtin_amdgcn_mfma_f32_16x16x32_bf16(a0, bfr[nt][0], z4, 0, 0, 0);
        c = __builtin_amdgcn_mfma_f32_16x16x32_bf16(a1, bfr[nt][1], c, 0, 0, 0);
        acc[mt][nt] = __builtin_amdgcn_mfma_f32_16x16x32_bf16(a2, baug[nt], c, 0, 0, 0);
      }
    }
    // ---- relu -> bf16 -> swizzled wave-private LDS, two nt-halves ----
    bf16x8 hbf[4][2];
#pragma unroll
    for (int hh = 0; hh < 2; hh++) {
#pragma unroll
      for (int mt = 0; mt < 4; mt++)
#pragma unroll
        for (int ntl = 0; ntl < 2; ntl++) {
          const f32x4 v = acc[mt][hh * 2 + ntl];
          uint2 dd;
          dd.x = pk2(fmaxf(v.x, 0.f), fmaxf(v.y, 0.f));
          dd.y = pk2(fmaxf(v.z, 0.f), fmaxf(v.w, 0.f));
          const int kb = (mt * 2 + (q >> 1)) ^ sw;
          *(uint2*)(hw + (ntl * 16 + col) * 64 + (kb << 3) + ((q & 1) << 2)) = dd;
        }
#pragma unroll
      for (int ntl = 0; ntl < 2; ntl++)
#pragma unroll
        for (int ks = 0; ks < 2; ks++)
          hbf[hh * 2 + ntl][ks] = *(const bf16x8*)(hw + (ntl * 16 + col) * 64 +
                                                   (((ks * 4 + q) ^ sw) << 3));
      // half 1 overwrites the same addresses; in-order DS per wave keeps RAW/WAR safe
    }
    // ---- layer 2 (C=b1) + layer 3 dot(w2, relu) fused per mt ----
    const float* vecf = (const float*)(wl + OFF_VEC);
    float s[4] = {0.f, 0.f, 0.f, 0.f};
#pragma unroll
    for (int mt = 0; mt < 4; mt++) {
      const bf16x8 a0 = *(const bf16x8*)(wl + OFF_W1 + (mt * 2 + 0) * 1024 + lane * 16);
      const bf16x8 a1 = *(const bf16x8*)(wl + OFF_W1 + (mt * 2 + 1) * 1024 + lane * 16);
      const int ro = mt * 16 + q * 4;
      const f32x4 cb  = *(const f32x4*)(vecf + ro);        // b1 broadcast
      const f32x4 w2v = *(const f32x4*)(vecf + 64 + ro);
#pragma unroll
      for (int nt = 0; nt < 4; nt++) {
        f32x4 c = __builtin_amdgcn_mfma_f32_16x16x32_bf16(a0, hbf[nt][0], cb, 0, 0, 0);
        const f32x4 v = __builtin_amdgcn_mfma_f32_16x16x32_bf16(a1, hbf[nt][1], c, 0, 0, 0);
        s[nt] += w2v.x * fmaxf(v.x, 0.f) + w2v.y * fmaxf(v.y, 0.f) +
                 w2v.z * fmaxf(v.z, 0.f) + w2v.w * fmaxf(v.w, 0.f);
      }
    }
    const float b2 = vecf[128];
#pragma unroll
    for (int nt = 0; nt < 4; nt++) {
      s[nt] += __shfl_xor(s[nt], 16, 64);
      s[nt] += __shfl_xor(s[nt], 32, 64);
    }
    const float sel = (q == 0) ? s[0] : (q == 1) ? s[1] : (q == 2) ? s[2] : s[3];
    outb[i * HW] = sel + b2;          // px = wave*64 + q*16 + col = wave*64+lane

    // swap in next instance's weights
    if (i < 7) {
      __syncthreads();               // all waves done reading wl
#pragma unroll
      for (int j = 0; j < 6; j++)
        if (j < 5 || tid < 64) *(uint4*)(wl + j * 4096 + tid * 16) = st[j];
      __syncthreads();               // writes visible
    }
  }
}

extern "C" void kernel_launch(void* const* d_in, const int* in_sizes, int n_in,
                              void* d_out, int out_size, void* d_ws, size_t ws_size,
                              hipStream_t stream) {
  const float* x      = (const float*)d_in[0];  // [4,64,160,256] fp32
  const float* params = (const float*)d_in[1];  // [32,8513] fp32
  // d_in[2] = num_ins (static 8/img; inst mapping hardcoded)
  float* out = (float*)d_out;

  condlane_prep<<<64, 256, 0, stream>>>(params, (char*)d_ws);   // 688 KB used
  condlane_main<<<dim3(160, 4), 256, 0, stream>>>(x, (const char*)d_ws, out);
}

// Round 8
// 141.910 us; speedup vs baseline: 1.0194x; 1.0194x over previous
//
#include <hip/hip_runtime.h>
#include <hip/hip_bf16.h>

// CondLaneHead via bf16 MFMA 16x16x32, 3 layers fused. Round 8.
// 32 instances (4 img x 8), C=64, H=160, W=256, L=40960 px.
//
// r7 lesson: nt=4 spilled (WRITE_SIZE 45MB). This round targets OCCUPANCY:
// nt=2 (128px/block, grid 1280 = exactly 5 blocks/CU), ~95 VGPR under a
// launch_bounds(256,5) cap, LDS 25.5KB -> 20 waves/CU (vs 8-12 all prior
// rounds). Weights stay LDS-staged (single buffer + reg prefetch, 2
// barriers/inst amortized over 5 co-resident blocks). x B-frags load
// straight from global to regs (no xs stage). h transform = r5-verified
// swizzled LDS round-trip, 2KB/wave, write/read/overwrite in-order per wave.
//
// Frag layouts (m89/m120-verified): A[m=lane&15][k=(lane>>4)*8+j],
// B[k=(lane>>4)*8+j][n=lane&15], D[row=(lane>>4)*4+r][col=lane&15].
//
// ws per instance (ISTRIDE=17920B):
//   [0,8192)      w0 A-frags, frag(mt,kst)=mt*2+kst, 1KB each (lane*16)
//   [8192,16384)  w1 A-frags, same layout
//   [16384,17920) vec: b0[64] wx[64] wy[64] b1[64] w2[64] b2 pad-to-384 (f32)

#define NP 8513
#define HW 40960
#define ISTRIDE 17920
#define OFF_W1 8192
#define OFF_VEC 16384

typedef __attribute__((ext_vector_type(8))) short bf16x8;
typedef __attribute__((ext_vector_type(4))) float f32x4;

__device__ inline unsigned short f2bf(float f) {
  union { float f; unsigned u; } v; v.f = f;
  unsigned r = v.u + 0x7fffu + ((v.u >> 16) & 1u);   // RNE
  return (unsigned short)(r >> 16);
}
__device__ inline unsigned pk2(float a, float b) {   // [lo=a, hi=b] bf16x2
  __hip_bfloat162 h = __float22bfloat162_rn(float2{a, b});
  union { __hip_bfloat162 h; unsigned u; } v; v.h = h;
  return v.u;
}

__global__ void condlane_prep(const float* __restrict__ params,
                              char* __restrict__ ws) {
  const int inst = blockIdx.x >> 1, part = blockIdx.x & 1;
  const float* __restrict__ p = params + inst * NP;
  char* base = ws + inst * ISTRIDE;
  const int t = threadIdx.x;
  if (part == 0) {           // w0 A-frags (K=64)
    unsigned short* dst = (unsigned short*)base;
#pragma unroll
    for (int it = 0; it < 16; it++) {
      const int e = it * 256 + t;
      const int frag = e >> 9, lane = (e >> 3) & 63, j = e & 7;
      const int m = (frag >> 1) * 16 + (lane & 15);
      const int k = (frag & 1) * 32 + ((lane >> 4) << 3) + j;
      dst[e] = f2bf(p[m * 66 + 2 + k]);
    }
  } else {                   // w1 A-frags + vec
    unsigned short* dst = (unsigned short*)(base + OFF_W1);
#pragma unroll
    for (int it = 0; it < 16; it++) {
      const int e = it * 256 + t;
      const int frag = e >> 9, lane = (e >> 3) & 63, j = e & 7;
      const int m = (frag >> 1) * 16 + (lane & 15);
      const int k = (frag & 1) * 32 + ((lane >> 4) << 3) + j;
      dst[e] = f2bf(p[4224 + m * 64 + k]);
    }
    float* vec = (float*)(base + OFF_VEC);
    if (t < 64) {
      vec[t]       = p[8384 + t];    // b0
      vec[64 + t]  = p[t * 66];      // wx
      vec[128 + t] = p[t * 66 + 1];  // wy
      vec[192 + t] = p[8448 + t];    // b1
      vec[256 + t] = p[8320 + t];    // w2
    } else if (t == 64) vec[320] = p[8512] - 2.19f;
    if (t >= 65 && t < 128) vec[256 + t] = 0.f;   // pad 321..383
  }
}

__global__ __launch_bounds__(256, 5) void condlane_main(
    const float* __restrict__ x, const char* __restrict__ ws,
    float* __restrict__ out) {
  // [0,16384) weights, [16384,17920) vec, [17920,26112) h (2KB/wave)
  __shared__ __align__(16) char smem[26112];
  char* const wl = smem;
  const float* const vec = (const float*)(smem + OFF_VEC);
  const int img = blockIdx.y, bx = blockIdx.x;   // bx: 128-px chunk (half row)
  const int tid = threadIdx.x, lane = tid & 63, wave = tid >> 6;
  const int col = lane & 15, q = lane >> 4, sw = col & 7;
  const char* const wsb = ws + img * 8 * ISTRIDE;

  // ---- issue instance-0 weight loads (L2) ----
  uint4 st[4]; uint4 stv;
  {
#pragma unroll
    for (int j = 0; j < 4; j++) st[j] = *(const uint4*)(wsb + j * 4096 + tid * 16);
    if (tid < 96) stv = *(const uint4*)(wsb + OFF_VEC + tid * 16);
  }
  // ---- x B-frags straight from global to regs (reused all 8 instances) ----
  bf16x8 bfr[2][2];
  {
    const float* gx = x + img * 64 * HW + bx * 128 + wave * 32;
#pragma unroll
    for (int nt = 0; nt < 2; nt++)
#pragma unroll
      for (int ks = 0; ks < 2; ks++) {
        float f[8];
#pragma unroll
        for (int j = 0; j < 8; j++)
          f[j] = gx[(ks * 32 + q * 8 + j) * HW + nt * 16 + col];
        union { bf16x8 v; unsigned d[4]; } u;
#pragma unroll
        for (int jj = 0; jj < 4; jj++) u.d[jj] = pk2(f[2 * jj], f[2 * jj + 1]);
        bfr[nt][ks] = u.v;
      }
  }
  // ---- stage instance-0 weights into LDS ----
#pragma unroll
  for (int j = 0; j < 4; j++) *(uint4*)(wl + j * 4096 + tid * 16) = st[j];
  if (tid < 96) *(uint4*)(smem + OFF_VEC + tid * 16) = stv;
  __syncthreads();

  const float fyv = (float)(bx >> 1);
  const float fx0 = (float)((bx & 1) * 128 + wave * 32 + col);
  unsigned short* const hwv = (unsigned short*)(smem + 17920) + wave * 1024;
  float* const outb = out + img * 8 * HW + bx * 128 + wave * 32;

  for (int i = 0; i < 8; i++) {
    // prefetch next instance's weights to regs (covers the whole compute)
    if (i < 7) {
      const char* src = wsb + (i + 1) * ISTRIDE;
#pragma unroll
      for (int j = 0; j < 4; j++) st[j] = *(const uint4*)(src + j * 4096 + tid * 16);
      if (tid < 96) stv = *(const uint4*)(src + OFF_VEC + tid * 16);
    }
    const float b2i = vec[320];

    // ---- layer 1: C-init = b0 + wy*fy + wx*fx (exact fp32), K=64 MFMA ----
    f32x4 acc[4][2];
#pragma unroll
    for (int mt = 0; mt < 4; mt++) {
      const int ro = mt * 16 + q * 4;
      const f32x4 b0v = *(const f32x4*)(vec + ro);        // broadcast b128
      const f32x4 wxv = *(const f32x4*)(vec + 64 + ro);
      const f32x4 wyv = *(const f32x4*)(vec + 128 + ro);
      const f32x4 byv = b0v + wyv * fyv;
      acc[mt][0] = byv + wxv * fx0;
      acc[mt][1] = byv + wxv * (fx0 + 16.0f);
    }
#pragma unroll
    for (int mt = 0; mt < 4; mt++) {
      const bf16x8 a0 = *(const bf16x8*)(wl + (mt * 2 + 0) * 1024 + lane * 16);
      const bf16x8 a1 = *(const bf16x8*)(wl + (mt * 2 + 1) * 1024 + lane * 16);
#pragma unroll
      for (int nt = 0; nt < 2; nt++) {
        f32x4 c = __builtin_amdgcn_mfma_f32_16x16x32_bf16(a0, bfr[nt][0],
                                                          acc[mt][nt], 0, 0, 0);
        acc[mt][nt] = __builtin_amdgcn_mfma_f32_16x16x32_bf16(a1, bfr[nt][1],
                                                              c, 0, 0, 0);
      }
    }
    // ---- relu -> bf16 -> swizzled wave-private LDS (2KB), per-nt halves ----
    bf16x8 hbf[2][2];
#pragma unroll
    for (int nt = 0; nt < 2; nt++) {
#pragma unroll
      for (int mt = 0; mt < 4; mt++) {
        const f32x4 v = acc[mt][nt];
        uint2 dd;
        dd.x = pk2(fmaxf(v.x, 0.f), fmaxf(v.y, 0.f));
        dd.y = pk2(fmaxf(v.z, 0.f), fmaxf(v.w, 0.f));
        const int kb = (mt * 2 + (q >> 1)) ^ sw;
        *(uint2*)(hwv + col * 64 + (kb << 3) + ((q & 1) << 2)) = dd;
      }
#pragma unroll
      for (int ks = 0; ks < 2; ks++)
        hbf[nt][ks] = *(const bf16x8*)(hwv + col * 64 + (((ks * 4 + q) ^ sw) << 3));
      // nt=1 overwrites same addrs; per-wave in-order DS keeps RAW/WAR safe
    }
    // ---- layer 2 (C=b1) + layer 3 dot(w2, relu) fused per mt ----
    float s0 = 0.f, s1 = 0.f;
#pragma unroll
    for (int mt = 0; mt < 4; mt++) {
      const bf16x8 a0 = *(const bf16x8*)(wl + OFF_W1 + (mt * 2 + 0) * 1024 + lane * 16);
      const bf16x8 a1 = *(const bf16x8*)(wl + OFF_W1 + (mt * 2 + 1) * 1024 + lane * 16);
      const int ro = mt * 16 + q * 4;
      const f32x4 cb  = *(const f32x4*)(vec + 192 + ro);
      const f32x4 w2v = *(const f32x4*)(vec + 256 + ro);
      f32x4 c0 = __builtin_amdgcn_mfma_f32_16x16x32_bf16(a0, hbf[0][0], cb, 0, 0, 0);
      const f32x4 v0 = __builtin_amdgcn_mfma_f32_16x16x32_bf16(a1, hbf[0][1], c0, 0, 0, 0);
      f32x4 c1 = __builtin_amdgcn_mfma_f32_16x16x32_bf16(a0, hbf[1][0], cb, 0, 0, 0);
      const f32x4 v1 = __builtin_amdgcn_mfma_f32_16x16x32_bf16(a1, hbf[1][1], c1, 0, 0, 0);
      s0 += w2v.x * fmaxf(v0.x, 0.f) + w2v.y * fmaxf(v0.y, 0.f) +
            w2v.z * fmaxf(v0.z, 0.f) + w2v.w * fmaxf(v0.w, 0.f);
      s1 += w2v.x * fmaxf(v1.x, 0.f) + w2v.y * fmaxf(v1.y, 0.f) +
            w2v.z * fmaxf(v1.z, 0.f) + w2v.w * fmaxf(v1.w, 0.f);
    }
    s0 += __shfl_xor(s0, 16, 64); s0 += __shfl_xor(s0, 32, 64);
    s1 += __shfl_xor(s1, 16, 64); s1 += __shfl_xor(s1, 32, 64);
    if (lane < 32)
      outb[i * HW + q * 16 + col] = (q ? s1 : s0) + b2i;

    // swap in next instance's weights (all waves done reading wl/vec)
    if (i < 7) {
      __syncthreads();
#pragma unroll
      for (int j = 0; j < 4; j++) *(uint4*)(wl + j * 4096 + tid * 16) = st[j];
      if (tid < 96) *(uint4*)(smem + OFF_VEC + tid * 16) = stv;
      __syncthreads();
    }
  }
}

extern "C" void kernel_launch(void* const* d_in, const int* in_sizes, int n_in,
                              void* d_out, int out_size, void* d_ws, size_t ws_size,
                              hipStream_t stream) {
  const float* x      = (const float*)d_in[0];  // [4,64,160,256] fp32
  const float* params = (const float*)d_in[1];  // [32,8513] fp32
  // d_in[2] = num_ins (static 8/img; inst mapping hardcoded)
  float* out = (float*)d_out;

  condlane_prep<<<64, 256, 0, stream>>>(params, (char*)d_ws);   // 573 KB used
  condlane_main<<<dim3(320, 4), 256, 0, stream>>>(x, (const char*)d_ws, out);
}

// Round 9
// 113.233 us; speedup vs baseline: 1.2775x; 1.2533x over previous
//
#include <hip/hip_runtime.h>
#include <hip/hip_bf16.h>

// CondLaneHead via bf16 MFMA 16x16x32, 3 layers fused. Round 9.
// 32 instances (4 img x 8), C=64, H=160, W=256, L=40960 px.
//
// r7/r8 lesson: kernel state needs ~110-125 VGPRs; any launch_bounds cap
// below that spills (r8: 102MB scratch). This round: launch_bounds(256,3)
// (cap ~170, no spill) and let LDS (52KB) govern occupancy at 3 blocks/CU.
// Weight staging via global_load_lds (16B) into a DOUBLE-buffered LDS region:
// no prefetch registers, no reg->LDS write pass, 1 barrier/instance. DMA for
// inst i+1 issues at top of inst i; the compiler's vmcnt(0) drain before
// s_barrier makes it visible; the previous barrier makes the WAR safe.
//
// Frag layouts (m89/m120-verified): A[m=lane&15][k=(lane>>4)*8+j],
// B[k=(lane>>4)*8+j][n=lane&15], D[row=(lane>>4)*4+r][col=lane&15].
//
// ws per instance (ISTRIDE=18432B):
//   [0,8192)      w0 A-frags, frag(mt,kst)=mt*2+kst, 1KB each (lane*16)
//   [8192,16384)  w1 A-frags, same layout
//   [16384,17668) vec f32: b0[64] wx[64] wy[64] b1[64] w2[64] b2
//   [17668,18432) pad (DMA'd, never read)

#define NP 8513
#define HW 40960
#define ISTRIDE 18432
#define OFF_W1 8192
#define OFF_VEC 16384

typedef __attribute__((ext_vector_type(8))) short bf16x8;
typedef __attribute__((ext_vector_type(4))) float f32x4;

__device__ inline unsigned short f2bf(float f) {
  union { float f; unsigned u; } v; v.f = f;
  unsigned r = v.u + 0x7fffu + ((v.u >> 16) & 1u);   // RNE
  return (unsigned short)(r >> 16);
}
__device__ inline unsigned pk2(float a, float b) {   // [lo=a, hi=b] bf16x2
  __hip_bfloat162 h = __float22bfloat162_rn(float2{a, b});
  union { __hip_bfloat162 h; unsigned u; } v; v.h = h;
  return v.u;
}
// async global->LDS, 16B/lane; lds dest is wave-uniform base (+lane*16 by HW)
__device__ inline void gld16(const void* g, void* l) {
  __builtin_amdgcn_global_load_lds(
      (const __attribute__((address_space(1))) unsigned*)g,
      (__attribute__((address_space(3))) unsigned*)l, 16, 0, 0);
}

__global__ void condlane_prep(const float* __restrict__ params,
                              char* __restrict__ ws) {
  const int inst = blockIdx.x >> 1, part = blockIdx.x & 1;
  const float* __restrict__ p = params + inst * NP;
  char* base = ws + inst * ISTRIDE;
  const int t = threadIdx.x;
  if (part == 0) {           // w0 A-frags (K=64)
    unsigned short* dst = (unsigned short*)base;
#pragma unroll
    for (int it = 0; it < 16; it++) {
      const int e = it * 256 + t;
      const int frag = e >> 9, lane = (e >> 3) & 63, j = e & 7;
      const int m = (frag >> 1) * 16 + (lane & 15);
      const int k = (frag & 1) * 32 + ((lane >> 4) << 3) + j;
      dst[e] = f2bf(p[m * 66 + 2 + k]);
    }
  } else {                   // w1 A-frags + vec
    unsigned short* dst = (unsigned short*)(base + OFF_W1);
#pragma unroll
    for (int it = 0; it < 16; it++) {
      const int e = it * 256 + t;
      const int frag = e >> 9, lane = (e >> 3) & 63, j = e & 7;
      const int m = (frag >> 1) * 16 + (lane & 15);
      const int k = (frag & 1) * 32 + ((lane >> 4) << 3) + j;
      dst[e] = f2bf(p[4224 + m * 64 + k]);
    }
    float* vec = (float*)(base + OFF_VEC);
    if (t < 64) {
      vec[t]       = p[8384 + t];    // b0
      vec[64 + t]  = p[t * 66];      // wx
      vec[128 + t] = p[t * 66 + 1];  // wy
      vec[192 + t] = p[8448 + t];    // b1
      vec[256 + t] = p[8320 + t];    // w2
    } else if (t == 64) vec[320] = p[8512] - 2.19f;
  }
}

__global__ __launch_bounds__(256, 3) void condlane_main(
    const float* __restrict__ x, const char* __restrict__ ws,
    float* __restrict__ out) {
  // [0,18432) weight buf0, [18432,36864) buf1, [36864,53248) h (4KB/wave)
  __shared__ __align__(16) char smem[53248];
  const int img = blockIdx.y, bx = blockIdx.x;   // bx: 128-px chunk
  const int tid = threadIdx.x, lane = tid & 63, wave = tid >> 6;
  const int col = lane & 15, q = lane >> 4, sw = col & 7;
  const char* const wsb = ws + img * 8 * ISTRIDE;

  // per-wave DMA of one instance's weights (4 units/wave + vec on waves 0,1)
  auto dma = [&](int i, char* buf) {
    const char* src = wsb + i * ISTRIDE;
#pragma unroll
    for (int u = 0; u < 4; u++) {
      const int off = (wave * 4 + u) * 1024;
      gld16(src + off + lane * 16, buf + off);
    }
    if (wave < 2) {
      const int off = OFF_VEC + wave * 1024;
      gld16(src + off + lane * 16, buf + off);
    }
  };
  dma(0, smem);   // inst-0 weights in flight during x loads

  // ---- x B-frags straight from global to regs (reused all 8 instances) ----
  bf16x8 bfr[2][2];
  {
    const float* gx = x + img * 64 * HW + bx * 128 + wave * 32;
#pragma unroll
    for (int nt = 0; nt < 2; nt++)
#pragma unroll
      for (int ks = 0; ks < 2; ks++) {
        float f[8];
#pragma unroll
        for (int j = 0; j < 8; j++)
          f[j] = gx[(ks * 32 + q * 8 + j) * HW + nt * 16 + col];
        union { bf16x8 v; unsigned d[4]; } u;
#pragma unroll
        for (int jj = 0; jj < 4; jj++) u.d[jj] = pk2(f[2 * jj], f[2 * jj + 1]);
        bfr[nt][ks] = u.v;
      }
  }
  __syncthreads();   // vmcnt(0)+barrier: inst-0 DMA landed, visible to all

  const float fyv = (float)(bx >> 1);
  const float fx0 = (float)((bx & 1) * 128 + wave * 32 + col);
  unsigned short* const hwv = (unsigned short*)(smem + 36864) + wave * 2048;
  float* const outb = out + img * 8 * HW + bx * 128 + wave * 32;

  for (int i = 0; i < 8; i++) {
    char* const wb = smem + (i & 1) * ISTRIDE;
    if (i < 7) dma(i + 1, smem + ((i + 1) & 1) * ISTRIDE);  // async fill
    const float* const vec = (const float*)(wb + OFF_VEC);

    // ---- layer 1: C-init = b0 + wy*fy + wx*fx (exact fp32), K=64 MFMA ----
    f32x4 acc[4][2];
#pragma unroll
    for (int mt = 0; mt < 4; mt++) {
      const int ro = mt * 16 + q * 4;
      const f32x4 b0v = *(const f32x4*)(vec + ro);       // broadcast b128
      const f32x4 wxv = *(const f32x4*)(vec + 64 + ro);
      const f32x4 wyv = *(const f32x4*)(vec + 128 + ro);
      const f32x4 byv = b0v + wyv * fyv;
      acc[mt][0] = byv + wxv * fx0;
      acc[mt][1] = byv + wxv * (fx0 + 16.0f);
    }
#pragma unroll
    for (int mt = 0; mt < 4; mt++) {
      const bf16x8 a0 = *(const bf16x8*)(wb + (mt * 2 + 0) * 1024 + lane * 16);
      const bf16x8 a1 = *(const bf16x8*)(wb + (mt * 2 + 1) * 1024 + lane * 16);
#pragma unroll
      for (int nt = 0; nt < 2; nt++) {
        f32x4 c = __builtin_amdgcn_mfma_f32_16x16x32_bf16(a0, bfr[nt][0],
                                                          acc[mt][nt], 0, 0, 0);
        acc[mt][nt] = __builtin_amdgcn_mfma_f32_16x16x32_bf16(a1, bfr[nt][1],
                                                              c, 0, 0, 0);
      }
    }
    // ---- relu -> bf16 -> swizzled wave-private LDS (4KB, both nt live) ----
#pragma unroll
    for (int nt = 0; nt < 2; nt++)
#pragma unroll
      for (int mt = 0; mt < 4; mt++) {
        const f32x4 v = acc[mt][nt];
        uint2 dd;
        dd.x = pk2(fmaxf(v.x, 0.f), fmaxf(v.y, 0.f));
        dd.y = pk2(fmaxf(v.z, 0.f), fmaxf(v.w, 0.f));
        const int kb = (mt * 2 + (q >> 1)) ^ sw;
        *(uint2*)(hwv + nt * 1024 + col * 64 + (kb << 3) + ((q & 1) << 2)) = dd;
      }
    bf16x8 hbf[2][2];   // same-wave RAW: compiler inserts precise lgkmcnt
#pragma unroll
    for (int nt = 0; nt < 2; nt++)
#pragma unroll
      for (int ks = 0; ks < 2; ks++)
        hbf[nt][ks] = *(const bf16x8*)(hwv + nt * 1024 + col * 64 +
                                       (((ks * 4 + q) ^ sw) << 3));

    // ---- layer 2 (C=b1) + layer 3 dot(w2, relu) fused per mt ----
    float s0 = 0.f, s1 = 0.f;
#pragma unroll
    for (int mt = 0; mt < 4; mt++) {
      const bf16x8 a0 = *(const bf16x8*)(wb + OFF_W1 + (mt * 2 + 0) * 1024 + lane * 16);
      const bf16x8 a1 = *(const bf16x8*)(wb + OFF_W1 + (mt * 2 + 1) * 1024 + lane * 16);
      const int ro = mt * 16 + q * 4;
      const f32x4 cb  = *(const f32x4*)(vec + 192 + ro);
      const f32x4 w2v = *(const f32x4*)(vec + 256 + ro);
      f32x4 c0 = __builtin_amdgcn_mfma_f32_16x16x32_bf16(a0, hbf[0][0], cb, 0, 0, 0);
      const f32x4 v0 = __builtin_amdgcn_mfma_f32_16x16x32_bf16(a1, hbf[0][1], c0, 0, 0, 0);
      f32x4 c1 = __builtin_amdgcn_mfma_f32_16x16x32_bf16(a0, hbf[1][0], cb, 0, 0, 0);
      const f32x4 v1 = __builtin_amdgcn_mfma_f32_16x16x32_bf16(a1, hbf[1][1], c1, 0, 0, 0);
      s0 += w2v.x * fmaxf(v0.x, 0.f) + w2v.y * fmaxf(v0.y, 0.f) +
            w2v.z * fmaxf(v0.z, 0.f) + w2v.w * fmaxf(v0.w, 0.f);
      s1 += w2v.x * fmaxf(v1.x, 0.f) + w2v.y * fmaxf(v1.y, 0.f) +
            w2v.z * fmaxf(v1.z, 0.f) + w2v.w * fmaxf(v1.w, 0.f);
    }
    const float b2i = vec[320];
    s0 += __shfl_xor(s0, 16, 64); s0 += __shfl_xor(s0, 32, 64);
    s1 += __shfl_xor(s1, 16, 64); s1 += __shfl_xor(s1, 32, 64);
    if (lane < 32)
      outb[i * HW + q * 16 + col] = (q ? s1 : s0) + b2i;

    // barrier: drains DMA (vmcnt0) so buf[(i+1)&1] is ready; also gates WAR
    if (i < 7) __syncthreads();
  }
}

extern "C" void kernel_launch(void* const* d_in, const int* in_sizes, int n_in,
                              void* d_out, int out_size, void* d_ws, size_t ws_size,
                              hipStream_t stream) {
  const float* x      = (const float*)d_in[0];  // [4,64,160,256] fp32
  const float* params = (const float*)d_in[1];  // [32,8513] fp32
  // d_in[2] = num_ins (static 8/img; inst mapping hardcoded)
  float* out = (float*)d_out;

  condlane_prep<<<64, 256, 0, stream>>>(params, (char*)d_ws);   // 590 KB used
  condlane_main<<<dim3(320, 4), 256, 0, stream>>>(x, (const char*)d_ws, out);
}